// Round 13
// baseline (3596.452 us; speedup 1.0000x reference)
//
#include <hip/hip_runtime.h>
#include <cstdint>
#include <cstddef>

#define DEV __device__ __forceinline__

typedef __attribute__((ext_vector_type(4))) float f32x4;
typedef __attribute__((ext_vector_type(8))) short bf16x8;
typedef unsigned short ushort_t;
typedef __attribute__((ext_vector_type(8))) unsigned short ushort8;

static constexpr int B_ = 16384, D_ = 1024, O_ = 2048;
static constexpr float LAM_ = 0.1f;

// ---------------- workspace layout (bytes) ----------------
static constexpr size_t WS_XBF   = 0;                               // B*D bf16
static constexpr size_t WS_XCBF  = WS_XBF   + (size_t)B_ * D_ * 2;  // B*D bf16
static constexpr size_t WS_HBF   = WS_XCBF  + (size_t)B_ * D_ * 2;  // B*D bf16
static constexpr size_t WS_CLSBF = WS_HBF   + (size_t)B_ * D_ * 2;  // O*D bf16
static constexpr size_t WS_CTWBF = WS_CLSBF + (size_t)O_ * D_ * 2;
static constexpr size_t WS_W2BF  = WS_CTWBF + (size_t)O_ * D_ * 2;
static constexpr size_t WS_W1BF  = WS_W2BF  + (size_t)O_ * D_ * 2;  // D*D bf16
static constexpr size_t WS_SMALL = WS_W1BF  + (size_t)D_ * D_ * 2;
// small block (byte offsets within WS_SMALL):
static constexpr size_t SM_COUNTS = 0;       // O f32   (zeroed)
static constexpr size_t SM_TSUM   = 8192;    // O f32   (zeroed)
static constexpr size_t SM_MSE    = 16384;   // B f32   (zeroed)
static constexpr size_t SM_ZERO_BYTES = 82176;
static constexpr size_t SM_S      = 82176;   // O f32   (fully overwritten)
static constexpr size_t SM_GWORD  = 90368;   // B f32   (fully overwritten)
static constexpr size_t SM_CEROW  = 155904;  // B f32   (fully overwritten)
// optional bf16 ctx buffer (used only if ws_size permits):
static constexpr size_t WS_CTXBF  = WS_SMALL + 2 * 1024 * 1024;
static constexpr size_t WS_NEED_BIG = WS_CTXBF + (size_t)B_ * O_ * 2;

// ---------------- helpers ----------------
DEV float wave_sum(float v) {
  #pragma unroll
  for (int o = 32; o; o >>= 1) v += __shfl_xor(v, o, 64);
  return v;
}

DEV ushort_t f2bf1(float f) {  // RNE float -> bf16 bits (finite inputs)
  union { float f; unsigned u; } c{f};
  unsigned r = c.u + 0x7fffu + ((c.u >> 16) & 1u);
  return (ushort_t)(r >> 16);
}

DEV float bf2f(ushort_t u) {
  union { unsigned u; float f; } c{(unsigned)u << 16};
  return c.f;
}

DEV float sigmoidf(float z) { return 1.0f / (1.0f + expf(-z)); }

DEV void gload_lds16(const ushort_t* g, ushort_t* l) {
  __builtin_amdgcn_global_load_lds((const __attribute__((address_space(1))) void*)g,
                                   (__attribute__((address_space(3))) void*)l, 16, 0, 0);
}

// stage a 128x32 tile with 256 threads (2 chunks each), T2-swizzled source quarter.
DEV void stage128s(const ushort_t* __restrict__ src, ushort_t* lds_, int tid) {
  int c0 = tid, c1 = tid + 256;
  int q0 = (c0 & 3) ^ ((c0 >> 3) & 3);
  int q1 = (c1 & 3) ^ ((c1 >> 3) & 3);
  gload_lds16(src + (size_t)(c0 >> 2) * 1024 + q0 * 8, lds_ + c0 * 8);
  gload_lds16(src + (size_t)(c1 >> 2) * 1024 + q1 * 8, lds_ + c1 * 8);
}

DEV f32x4 mfma16(bf16x8 a, bf16x8 b, f32x4 c) {
  return __builtin_amdgcn_mfma_f32_16x16x32_bf16(a, b, c, 0, 0, 0);
}

// ---------------- K1: f32 -> bf16 convert (8 elems/thread) ----------------
__global__ __launch_bounds__(256) void f2bf_kernel(const float* __restrict__ in,
                                                   ushort_t* __restrict__ out, int n8) {
  int i = blockIdx.x * 256 + threadIdx.x;
  if (i >= n8) return;
  const float4* p = (const float4*)(in + (size_t)i * 8);
  float4 a = p[0], b = p[1];
  ushort8 o;
  o[0] = f2bf1(a.x); o[1] = f2bf1(a.y); o[2] = f2bf1(a.z); o[3] = f2bf1(a.w);
  o[4] = f2bf1(b.x); o[5] = f2bf1(b.y); o[6] = f2bf1(b.z); o[7] = f2bf1(b.w);
  *(ushort8*)(out + (size_t)i * 8) = o;
}

// ---------------- K2: fused x->bf16 convert + per-row dots ----------------
__global__ __launch_bounds__(256) void rowdot_cvt_kernel(const float* __restrict__ x,
    const float* __restrict__ cls, const float* __restrict__ wg,
    const float* __restrict__ wgb, const int* __restrict__ labels,
    ushort_t* __restrict__ xbf,
    float* __restrict__ tsum, float* __restrict__ counts, float* __restrict__ g_word) {
  int wave = threadIdx.x >> 6, lane = threadIdx.x & 63;
  int row = blockIdx.x * 4 + wave;
  const float* xr = x + (size_t)row * D_;
  int lab = labels[row];
  const float* cr = cls + (size_t)max(lab, 0) * D_;
  float t = 0.f, g = 0.f;
  #pragma unroll
  for (int j = 0; j < 4; ++j) {
    int d = j * 256 + lane * 4;
    float4 xv = *(const float4*)(xr + d);
    float4 cv = *(const float4*)(cr + d);
    float4 wv = *(const float4*)(wg + d);
    t += xv.x * cv.x + xv.y * cv.y + xv.z * cv.z + xv.w * cv.w;
    g += xv.x * wv.x + xv.y * wv.y + xv.z * wv.z + xv.w * wv.w;
    uint2 pk;
    pk.x = (unsigned)f2bf1(xv.x) | ((unsigned)f2bf1(xv.y) << 16);
    pk.y = (unsigned)f2bf1(xv.z) | ((unsigned)f2bf1(xv.w) << 16);
    *(uint2*)(xbf + (size_t)row * D_ + d) = pk;
  }
  t = wave_sum(t); g = wave_sum(g);
  if (lane == 0) {
    if (lab >= 0) {
      atomicAdd(&tsum[lab], t);
      atomicAdd(&counts[lab], 1.0f);
    }
    g_word[row] = sigmoidf(g + wgb[0]);
  }
}

// ---------------- K3: s[o] = dot(r_sub[o], classifier[o]) ----------------
__global__ __launch_bounds__(256) void scls_kernel(const float* __restrict__ cls,
    const float* __restrict__ none_t, const float* __restrict__ hist,
    const int* __restrict__ hcnt, const float* __restrict__ counts,
    const float* __restrict__ tsum, float* __restrict__ s) {
  int wave = threadIdx.x >> 6, lane = threadIdx.x & 63;
  int o = blockIdx.x * 4 + wave;
  if (o >= O_) return;
  const float* cr = cls + (size_t)o * D_;
  const float* src = (o == 0) ? none_t : hist + (size_t)(o - 1) * D_;
  float dv = 0.f;
  #pragma unroll
  for (int j = 0; j < 4; ++j) {
    int d = j * 256 + lane * 4;
    float4 a = *(const float4*)(src + d);
    float4 c = *(const float4*)(cr + d);
    dv += a.x * c.x + a.y * c.y + a.z * c.z + a.w * c.w;
  }
  dv = wave_sum(dv);
  if (lane == 0) {
    if (o == 0) { s[0] = dv; }
    else {
      float co = counts[o];
      bool has = co > 0.f;
      int cnt = hcnt[o - 1] + (has ? 1 : 0);
      float denom = 1.f - powf(0.9f, (float)max(cnt, 1));
      float val = has ? (0.9f * dv + tsum[o] / fmaxf(co, 1.f)) : dv;
      s[o] = (0.1f / denom) * val;
    }
  }
}

// ======== unified m97-style 128x128 2-phase GEMM ========
// r13: __launch_bounds__(256, 8) — remove the artificial 3-block/CU cap.
// VGPR=64 / LDS=16KB supports 8 blocks/CU; cross-block wave overlap (m114)
// hides the per-K-step vmcnt(0)+barrier drain and the epilogue HBM bursts.
// EPI: 0 = h (bias+gelu -> bf16 hout, N=1024)
//      1 = ctx (bias -> bf16 ctxbf if CTXB else f32 out1)
//      2 = att (bias; ctx re-read; per-row mse partials via atomics)
//      3 = xc  (ctx re-read; w = gw*sigmoid(ctx); out1 = (1-w)*xc + w*s)
template<int EPI, int NBN, bool CTXB>
__global__ __launch_bounds__(256, 8) void gemm128_kernel(
    const ushort_t* __restrict__ A, const ushort_t* __restrict__ Bmat,
    const float* __restrict__ bias, float* __restrict__ fout,
    ushort_t* __restrict__ hout, ushort_t* __restrict__ ctxbf,
    const float* __restrict__ g_word, const float* __restrict__ svec,
    float* __restrict__ mse_row) {
  __shared__ __align__(16) ushort_t As[128 * 32], Bs[128 * 32];
  const int tid = threadIdx.x, lane = tid & 63, wave = tid >> 6;
  const int wr = wave >> 1, wc = wave & 1;  // 2x2 waves, 64x64 per wave
  int bid = blockIdx.x;
  // L2 grouping: groups of 8 m-tiles x NBN n-tiles
  int group = bid / (8 * NBN), within = bid % (8 * NBN);
  int bm = group * 8 + (within & 7);
  int bn = within >> 3;
  const int NCOL = NBN * 128;
  f32x4 acc[4][4] = {};
  const ushort_t* Ap = A + (size_t)bm * 128 * 1024;
  const ushort_t* Bp = Bmat + (size_t)bn * 128 * 1024;
  const int r = lane & 15;
  const int qrd8 = ((lane >> 4) ^ ((r >> 1) & 3)) * 8;  // T2 read-side involution
  for (int k0 = 0; k0 < 1024; k0 += 32) {
    stage128s(Ap + k0, As, tid);
    stage128s(Bp + k0, Bs, tid);
    asm volatile("s_waitcnt vmcnt(0)" ::: "memory");
    __builtin_amdgcn_s_barrier();
    bf16x8 af[4], bf[4];
    #pragma unroll
    for (int m = 0; m < 4; m++) af[m] = *(const bf16x8*)&As[(wr * 64 + m * 16 + r) * 32 + qrd8];
    #pragma unroll
    for (int n = 0; n < 4; n++) bf[n] = *(const bf16x8*)&Bs[(wc * 64 + n * 16 + r) * 32 + qrd8];
    #pragma unroll
    for (int m = 0; m < 4; m++)
      #pragma unroll
      for (int n = 0; n < 4; n++) acc[m][n] = mfma16(af[m], bf[n], acc[m][n]);
    __builtin_amdgcn_s_barrier();
  }
  // ---- epilogue ----
  #pragma unroll
  for (int m = 0; m < 4; m++) {
    #pragma unroll
    for (int i = 0; i < 4; i++) {
      int row = bm * 128 + wr * 64 + m * 16 + (lane >> 4) * 4 + i;
      float gw = 0.f, msum = 0.f;
      if constexpr (EPI == 3) gw = g_word[row];
      #pragma unroll
      for (int n = 0; n < 4; n++) {
        int col = bn * 128 + wc * 64 + n * 16 + (lane & 15);
        float v = acc[m][n][i];
        if constexpr (EPI == 0) {
          float z = v + bias[col];
          float gl = 0.5f * z * (1.f + erff(z * 0.70710678118f));
          hout[(size_t)row * 1024 + col] = f2bf1(gl);
        } else if constexpr (EPI == 1) {
          float z = v + bias[col];
          if constexpr (CTXB) ctxbf[(size_t)row * O_ + col] = f2bf1(z);
          else                fout[(size_t)row * NCOL + col] = z;
        } else if constexpr (EPI == 2) {
          float att = v + bias[col];
          float ctx = CTXB ? bf2f(ctxbf[(size_t)row * O_ + col])
                           : fout[(size_t)row * NCOL + col];
          float d = ctx - att;
          msum += d * d;
        } else {
          size_t off = (size_t)row * NCOL + col;
          float ctx = CTXB ? bf2f(ctxbf[(size_t)row * O_ + col]) : fout[off];
          float w = gw * sigmoidf(ctx);
          fout[off] = (1.f - w) * v + w * svec[col];
        }
      }
      if constexpr (EPI == 2) {
        #pragma unroll
        for (int o = 1; o < 16; o <<= 1) msum += __shfl_xor(msum, o, 64);
        if ((lane & 15) == 0) atomicAdd(&mse_row[row], msum);
      }
    }
  }
}

// ---------------- K7: per-row log-softmax CE ----------------
__global__ __launch_bounds__(256) void ce_kernel(const float* __restrict__ logits,
    const int* __restrict__ labels, float* __restrict__ ce_row) {
  int row = blockIdx.x, t = threadIdx.x, lane = t & 63, wave = t >> 6;
  const float* lr = logits + (size_t)row * O_;
  float v[8];
  float m = -INFINITY;
  #pragma unroll
  for (int j = 0; j < 8; j++) { v[j] = lr[t + j * 256]; m = fmaxf(m, v[j]); }
  #pragma unroll
  for (int o = 32; o; o >>= 1) m = fmaxf(m, __shfl_xor(m, o, 64));
  __shared__ float red[8];
  if (lane == 0) red[wave] = m;
  __syncthreads();
  m = fmaxf(fmaxf(red[0], red[1]), fmaxf(red[2], red[3]));
  float se = 0.f;
  #pragma unroll
  for (int j = 0; j < 8; j++) se += expf(v[j] - m);
  se = wave_sum(se);
  if (lane == 0) red[4 + wave] = se;
  __syncthreads();
  if (t == 0) {
    float bs = red[4] + red[5] + red[6] + red[7];
    int lab = labels[row];
    float nll = 0.f;
    if (lab >= 0) nll = -(lr[lab] - m - logf(bs));
    ce_row[row] = nll;
  }
}

// ---------------- K8: final scalar ----------------
__global__ __launch_bounds__(256) void finalize_kernel(const float* __restrict__ ce_row,
    const float* __restrict__ mse_row, const int* __restrict__ labels,
    float* __restrict__ out0) {
  int t = threadIdx.x, lane = t & 63, wave = t >> 6;
  float sn = 0.f, sm = 0.f, sc = 0.f;
  for (int i = t; i < B_; i += 256) {
    if (labels[i] >= 0) { sn += ce_row[i]; sm += mse_row[i]; sc += 1.f; }
  }
  sn = wave_sum(sn); sm = wave_sum(sm); sc = wave_sum(sc);
  __shared__ float r0[4], r1[4], r2[4];
  if (lane == 0) { r0[wave] = sn; r1[wave] = sm; r2[wave] = sc; }
  __syncthreads();
  if (t == 0) {
    float a = r0[0] + r0[1] + r0[2] + r0[3];
    float b = r1[0] + r1[1] + r1[2] + r1[3];
    float c = r2[0] + r2[1] + r2[2] + r2[3];
    out0[0] = (a + LAM_ * (b / (float)O_)) / fmaxf(c, 1.f);
  }
}

// ---------------- launch ----------------
extern "C" void kernel_launch(void* const* d_in, const int* in_sizes, int n_in,
                              void* d_out, int out_size, void* d_ws, size_t ws_size,
                              hipStream_t stream) {
  const float* x        = (const float*)d_in[0];
  const float* x_ctx    = (const float*)d_in[1];
  const float* cls      = (const float*)d_in[2];
  const float* none_t   = (const float*)d_in[3];
  const float* ctx_q_w  = (const float*)d_in[4];
  const float* ctx_q_b  = (const float*)d_in[5];
  const float* word_g_w = (const float*)d_in[6];
  const float* word_g_b = (const float*)d_in[7];
  const float* w1       = (const float*)d_in[8];
  const float* b1       = (const float*)d_in[9];
  const float* w2       = (const float*)d_in[10];
  const float* b2       = (const float*)d_in[11];
  const float* hist     = (const float*)d_in[12];
  const int*   hcnt     = (const int*)d_in[13];
  const int*   labels   = (const int*)d_in[14];

  float* out  = (float*)d_out;
  float* out1 = out + 1;  // logits [B x O]
  char* ws = (char*)d_ws;

  ushort_t* xbf   = (ushort_t*)(ws + WS_XBF);
  ushort_t* xcbf  = (ushort_t*)(ws + WS_XCBF);
  ushort_t* hbf   = (ushort_t*)(ws + WS_HBF);
  ushort_t* clsbf = (ushort_t*)(ws + WS_CLSBF);
  ushort_t* ctwbf = (ushort_t*)(ws + WS_CTWBF);
  ushort_t* w2bf  = (ushort_t*)(ws + WS_W2BF);
  ushort_t* w1bf  = (ushort_t*)(ws + WS_W1BF);
  float* counts   = (float*)(ws + WS_SMALL + SM_COUNTS);
  float* tsum     = (float*)(ws + WS_SMALL + SM_TSUM);
  float* mse_row  = (float*)(ws + WS_SMALL + SM_MSE);
  float* s        = (float*)(ws + WS_SMALL + SM_S);
  float* g_word   = (float*)(ws + WS_SMALL + SM_GWORD);
  float* ce_row   = (float*)(ws + WS_SMALL + SM_CEROW);
  ushort_t* ctxbf = (ushort_t*)(ws + WS_CTXBF);
  const bool big  = ws_size >= WS_NEED_BIG;

  hipMemsetAsync(ws + WS_SMALL, 0, SM_ZERO_BYTES, stream);

  // fused: x -> bf16 + per-row dots
  rowdot_cvt_kernel<<<B_ / 4, 256, 0, stream>>>(x, cls, word_g_w, word_g_b, labels,
                                                xbf, tsum, counts, g_word);
  f2bf_kernel<<<8192, 256, 0, stream>>>(x_ctx, xcbf, B_ * D_ / 8);
  f2bf_kernel<<<1024, 256, 0, stream>>>(cls, clsbf, O_ * D_ / 8);
  f2bf_kernel<<<1024, 256, 0, stream>>>(ctx_q_w, ctwbf, O_ * D_ / 8);
  f2bf_kernel<<<1024, 256, 0, stream>>>(w2, w2bf, O_ * D_ / 8);
  f2bf_kernel<<<512, 256, 0, stream>>>(w1, w1bf, D_ * D_ / 8);

  scls_kernel<<<O_ / 4, 256, 0, stream>>>(cls, none_t, hist, hcnt, counts, tsum, s);

  // h = gelu(x @ w1^T + b1)   grid 128 x 8
  gemm128_kernel<0, 8, false><<<1024, 256, 0, stream>>>(xbf, w1bf, b1, nullptr, hbf,
                                                        nullptr, nullptr, nullptr, nullptr);
  // ctx = x_ctx @ ctx_q_w^T + ctx_b   grid 128 x 16
  if (big)
    gemm128_kernel<1, 16, true><<<2048, 256, 0, stream>>>(xcbf, ctwbf, ctx_q_b, out1,
                                                          nullptr, ctxbf, nullptr, nullptr,
                                                          nullptr);
  else
    gemm128_kernel<1, 16, false><<<2048, 256, 0, stream>>>(xcbf, ctwbf, ctx_q_b, out1,
                                                           nullptr, nullptr, nullptr, nullptr,
                                                           nullptr);
  // att = h @ w2^T + b2 ; mse partials vs ctx
  if (big)
    gemm128_kernel<2, 16, true><<<2048, 256, 0, stream>>>(hbf, w2bf, b2, out1,
                                                          nullptr, ctxbf, nullptr, nullptr,
                                                          mse_row);
  else
    gemm128_kernel<2, 16, false><<<2048, 256, 0, stream>>>(hbf, w2bf, b2, out1,
                                                           nullptr, nullptr, nullptr, nullptr,
                                                           mse_row);
  // xc = x @ cls^T ; gated combine
  if (big)
    gemm128_kernel<3, 16, true><<<2048, 256, 0, stream>>>(xbf, clsbf, nullptr, out1,
                                                          nullptr, ctxbf, g_word, s,
                                                          nullptr);
  else
    gemm128_kernel<3, 16, false><<<2048, 256, 0, stream>>>(xbf, clsbf, nullptr, out1,
                                                           nullptr, nullptr, g_word, s,
                                                           nullptr);

  ce_kernel<<<B_, 256, 0, stream>>>(out1, labels, ce_row);
  finalize_kernel<<<1, 256, 0, stream>>>(ce_row, mse_row, labels, out);
}

// Round 14
// 428.838 us; speedup vs baseline: 8.3865x; 8.3865x over previous
//
#include <hip/hip_runtime.h>
#include <cstdint>
#include <cstddef>

#define DEV __device__ __forceinline__

typedef __attribute__((ext_vector_type(4))) float f32x4;
typedef __attribute__((ext_vector_type(8))) short bf16x8;
typedef unsigned short ushort_t;
typedef __attribute__((ext_vector_type(8))) unsigned short ushort8;

static constexpr int B_ = 16384, D_ = 1024, O_ = 2048;
static constexpr float LAM_ = 0.1f;

// ---------------- workspace layout (bytes) ----------------
static constexpr size_t WS_XBF   = 0;                               // B*D bf16
static constexpr size_t WS_XCBF  = WS_XBF   + (size_t)B_ * D_ * 2;  // B*D bf16
static constexpr size_t WS_HBF   = WS_XCBF  + (size_t)B_ * D_ * 2;  // B*D bf16
static constexpr size_t WS_CLSBF = WS_HBF   + (size_t)B_ * D_ * 2;  // O*D bf16
static constexpr size_t WS_CTWBF = WS_CLSBF + (size_t)O_ * D_ * 2;
static constexpr size_t WS_W2BF  = WS_CTWBF + (size_t)O_ * D_ * 2;
static constexpr size_t WS_W1BF  = WS_W2BF  + (size_t)O_ * D_ * 2;  // D*D bf16
static constexpr size_t WS_SMALL = WS_W1BF  + (size_t)D_ * D_ * 2;
// small block (byte offsets within WS_SMALL):
static constexpr size_t SM_COUNTS = 0;       // O f32   (zeroed)
static constexpr size_t SM_TSUM   = 8192;    // O f32   (zeroed)
static constexpr size_t SM_MSE    = 16384;   // B f32   (zeroed)
static constexpr size_t SM_ZERO_BYTES = 82176;
static constexpr size_t SM_S      = 82176;   // O f32   (fully overwritten)
static constexpr size_t SM_GWORD  = 90368;   // B f32   (fully overwritten)
static constexpr size_t SM_CEROW  = 155904;  // B f32   (fully overwritten)
// optional bf16 ctx buffer (used only if ws_size permits):
static constexpr size_t WS_CTXBF  = WS_SMALL + 2 * 1024 * 1024;
static constexpr size_t WS_NEED_BIG = WS_CTXBF + (size_t)B_ * O_ * 2;

// ---------------- helpers ----------------
DEV float wave_sum(float v) {
  #pragma unroll
  for (int o = 32; o; o >>= 1) v += __shfl_xor(v, o, 64);
  return v;
}

DEV ushort_t f2bf1(float f) {  // RNE float -> bf16 bits (finite inputs)
  union { float f; unsigned u; } c{f};
  unsigned r = c.u + 0x7fffu + ((c.u >> 16) & 1u);
  return (ushort_t)(r >> 16);
}

DEV float bf2f(ushort_t u) {
  union { unsigned u; float f; } c{(unsigned)u << 16};
  return c.f;
}

DEV float sigmoidf(float z) { return 1.0f / (1.0f + expf(-z)); }

DEV void gload_lds16(const ushort_t* g, ushort_t* l) {
  __builtin_amdgcn_global_load_lds((const __attribute__((address_space(1))) void*)g,
                                   (__attribute__((address_space(3))) void*)l, 16, 0, 0);
}

// stage one 256x32 bf16 K-half slot (16 KB) with 512 threads (2 x 16B chunks).
// T2: LDS dest linear, SOURCE quarter pre-swizzled; ds_read applies same involution.
DEV void stage2(const ushort_t* __restrict__ s0, ushort_t* slot, int tid) {
  gload_lds16(s0, slot + tid * 8);
  gload_lds16(s0 + 128 * 1024, slot + (tid + 512) * 8);
}

// stage a 128x32 tile with 256 threads (2 chunks each), T2-swizzled source quarter.
DEV void stage128s(const ushort_t* __restrict__ src, ushort_t* lds_, int tid) {
  int c0 = tid, c1 = tid + 256;
  int q0 = (c0 & 3) ^ ((c0 >> 3) & 3);
  int q1 = (c1 & 3) ^ ((c1 >> 3) & 3);
  gload_lds16(src + (size_t)(c0 >> 2) * 1024 + q0 * 8, lds_ + c0 * 8);
  gload_lds16(src + (size_t)(c1 >> 2) * 1024 + q1 * 8, lds_ + c1 * 8);
}

DEV f32x4 mfma16(bf16x8 a, bf16x8 b, f32x4 c) {
  return __builtin_amdgcn_mfma_f32_16x16x32_bf16(a, b, c, 0, 0, 0);
}

template<int N> DEV void wait_vm() {
  if constexpr (N == 8)      asm volatile("s_waitcnt vmcnt(8)" ::: "memory");
  else if constexpr (N == 4) asm volatile("s_waitcnt vmcnt(4)" ::: "memory");
  else if constexpr (N == 0) asm volatile("s_waitcnt vmcnt(0)" ::: "memory");
}

// ---------------- K1: multi-range f32 -> bf16 convert (1 launch for 5 arrays) ----------------
// ranges (in 8-elem items): x_ctx 2M, cls 2M(?) see launch; all counts multiples of 256.
__global__ __launch_bounds__(256) void f2bf_multi_kernel(
    const float* __restrict__ s0, ushort_t* __restrict__ d0, int c0,
    const float* __restrict__ s1, ushort_t* __restrict__ d1, int c1,
    const float* __restrict__ s2, ushort_t* __restrict__ d2, int c2,
    const float* __restrict__ s3, ushort_t* __restrict__ d3, int c3,
    const float* __restrict__ s4, ushort_t* __restrict__ d4, int c4) {
  int i = blockIdx.x * 256 + threadIdx.x;
  const float* src; ushort_t* dst; int off;
  if (i < c0)      { src = s0; dst = d0; off = i; }
  else if (i < c1) { src = s1; dst = d1; off = i - c0; }
  else if (i < c2) { src = s2; dst = d2; off = i - c1; }
  else if (i < c3) { src = s3; dst = d3; off = i - c2; }
  else if (i < c4) { src = s4; dst = d4; off = i - c3; }
  else return;
  const float4* p = (const float4*)(src + (size_t)off * 8);
  float4 a = p[0], b = p[1];
  ushort8 o;
  o[0] = f2bf1(a.x); o[1] = f2bf1(a.y); o[2] = f2bf1(a.z); o[3] = f2bf1(a.w);
  o[4] = f2bf1(b.x); o[5] = f2bf1(b.y); o[6] = f2bf1(b.z); o[7] = f2bf1(b.w);
  *(ushort8*)(dst + (size_t)off * 8) = o;
}

// ---------------- K2: fused x->bf16 convert + per-row dots ----------------
__global__ __launch_bounds__(256) void rowdot_cvt_kernel(const float* __restrict__ x,
    const float* __restrict__ cls, const float* __restrict__ wg,
    const float* __restrict__ wgb, const int* __restrict__ labels,
    ushort_t* __restrict__ xbf,
    float* __restrict__ tsum, float* __restrict__ counts, float* __restrict__ g_word) {
  int wave = threadIdx.x >> 6, lane = threadIdx.x & 63;
  int row = blockIdx.x * 4 + wave;
  const float* xr = x + (size_t)row * D_;
  int lab = labels[row];
  const float* cr = cls + (size_t)max(lab, 0) * D_;
  float t = 0.f, g = 0.f;
  #pragma unroll
  for (int j = 0; j < 4; ++j) {
    int d = j * 256 + lane * 4;
    float4 xv = *(const float4*)(xr + d);
    float4 cv = *(const float4*)(cr + d);
    float4 wv = *(const float4*)(wg + d);
    t += xv.x * cv.x + xv.y * cv.y + xv.z * cv.z + xv.w * cv.w;
    g += xv.x * wv.x + xv.y * wv.y + xv.z * wv.z + xv.w * wv.w;
    uint2 pk;
    pk.x = (unsigned)f2bf1(xv.x) | ((unsigned)f2bf1(xv.y) << 16);
    pk.y = (unsigned)f2bf1(xv.z) | ((unsigned)f2bf1(xv.w) << 16);
    *(uint2*)(xbf + (size_t)row * D_ + d) = pk;
  }
  t = wave_sum(t); g = wave_sum(g);
  if (lane == 0) {
    if (lab >= 0) {
      atomicAdd(&tsum[lab], t);
      atomicAdd(&counts[lab], 1.0f);
    }
    g_word[row] = sigmoidf(g + wgb[0]);
  }
}

// ---------------- K3: s[o] = dot(r_sub[o], classifier[o]) ----------------
__global__ __launch_bounds__(256) void scls_kernel(const float* __restrict__ cls,
    const float* __restrict__ none_t, const float* __restrict__ hist,
    const int* __restrict__ hcnt, const float* __restrict__ counts,
    const float* __restrict__ tsum, float* __restrict__ s) {
  int wave = threadIdx.x >> 6, lane = threadIdx.x & 63;
  int o = blockIdx.x * 4 + wave;
  if (o >= O_) return;
  const float* cr = cls + (size_t)o * D_;
  const float* src = (o == 0) ? none_t : hist + (size_t)(o - 1) * D_;
  float dv = 0.f;
  #pragma unroll
  for (int j = 0; j < 4; ++j) {
    int d = j * 256 + lane * 4;
    float4 a = *(const float4*)(src + d);
    float4 c = *(const float4*)(cr + d);
    dv += a.x * c.x + a.y * c.y + a.z * c.z + a.w * c.w;
  }
  dv = wave_sum(dv);
  if (lane == 0) {
    if (o == 0) { s[0] = dv; }
    else {
      float co = counts[o];
      bool has = co > 0.f;
      int cnt = hcnt[o - 1] + (has ? 1 : 0);
      float denom = 1.f - powf(0.9f, (float)max(cnt, 1));
      float val = has ? (0.9f * dv + tsum[o] / fmaxf(co, 1.f)) : dv;
      s[o] = (0.1f / denom) * val;
    }
  }
}

// ---------------- r5 8-phase 256x256 GEMM (frozen schedule) ----------------
template<bool S01, bool S23, int W1, int W3>
DEV void tile8(int t, const ushort_t* __restrict__ sA0, const ushort_t* __restrict__ sB0,
               ushort_t* lds, int tid, int aoff, int boff, f32x4 (&acc)[8][4]) {
  const int k0 = 2 * t, k1 = 2 * t + 1;
  const ushort_t* As0 = lds + (k0 & 3) * 8192;
  const ushort_t* Bs0 = lds + 32768 + (k0 & 3) * 8192;
  const ushort_t* As1 = lds + (k1 & 3) * 8192;
  const ushort_t* Bs1 = lds + 32768 + (k1 & 3) * 8192;
  bf16x8 afr[4], bfr[4];
  #pragma unroll
  for (int n = 0; n < 4; n++) bfr[n] = *(const bf16x8*)&Bs0[boff + n * 512];
  #pragma unroll
  for (int m = 0; m < 4; m++) afr[m] = *(const bf16x8*)&As0[aoff + m * 512];
  if constexpr (S01) stage2(sA0 + (size_t)(2 * t + 3) * 32, lds + ((2 * t + 3) & 3) * 8192, tid);
  __builtin_amdgcn_s_barrier();
  __builtin_amdgcn_s_setprio(1);
  #pragma unroll
  for (int m = 0; m < 4; m++)
    #pragma unroll
    for (int n = 0; n < 4; n++) acc[m][n] = mfma16(afr[m], bfr[n], acc[m][n]);
  __builtin_amdgcn_s_setprio(0);
  __builtin_amdgcn_s_barrier();
  #pragma unroll
  for (int m = 0; m < 4; m++) afr[m] = *(const bf16x8*)&As0[aoff + (m + 4) * 512];
  if constexpr (S01) stage2(sB0 + (size_t)(2 * t + 3) * 32, lds + 32768 + ((2 * t + 3) & 3) * 8192, tid);
  __builtin_amdgcn_s_barrier();
  __builtin_amdgcn_s_setprio(1);
  #pragma unroll
  for (int m = 0; m < 4; m++)
    #pragma unroll
    for (int n = 0; n < 4; n++) acc[m + 4][n] = mfma16(afr[m], bfr[n], acc[m + 4][n]);
  __builtin_amdgcn_s_setprio(0);
  wait_vm<W1>();
  __builtin_amdgcn_s_barrier();
  #pragma unroll
  for (int n = 0; n < 4; n++) bfr[n] = *(const bf16x8*)&Bs1[boff + n * 512];
  #pragma unroll
  for (int m = 0; m < 4; m++) afr[m] = *(const bf16x8*)&As1[aoff + m * 512];
  if constexpr (S23) stage2(sA0 + (size_t)(2 * t + 4) * 32, lds + ((2 * t + 4) & 3) * 8192, tid);
  __builtin_amdgcn_s_barrier();
  __builtin_amdgcn_s_setprio(1);
  #pragma unroll
  for (int m = 0; m < 4; m++)
    #pragma unroll
    for (int n = 0; n < 4; n++) acc[m][n] = mfma16(afr[m], bfr[n], acc[m][n]);
  __builtin_amdgcn_s_setprio(0);
  __builtin_amdgcn_s_barrier();
  #pragma unroll
  for (int m = 0; m < 4; m++) afr[m] = *(const bf16x8*)&As1[aoff + (m + 4) * 512];
  if constexpr (S23) stage2(sB0 + (size_t)(2 * t + 4) * 32, lds + 32768 + ((2 * t + 4) & 3) * 8192, tid);
  __builtin_amdgcn_s_barrier();
  __builtin_amdgcn_s_setprio(1);
  #pragma unroll
  for (int m = 0; m < 4; m++)
    #pragma unroll
    for (int n = 0; n < 4; n++) acc[m + 4][n] = mfma16(afr[m], bfr[n], acc[m + 4][n]);
  __builtin_amdgcn_s_setprio(0);
  wait_vm<W3>();
  __builtin_amdgcn_s_barrier();
}

// EPI: 0 = h (bias+gelu -> bf16 hout); 1 = ctx (bias -> bf16 ctxbf or f32 fout)
//      3 = xc (read ctx; w = gw*sigmoid(ctx); fout = (1-w)*xc + w*s)
template<int EPI, int NTSHIFT, bool CTXB>
__global__ __launch_bounds__(512, 2) void gemm8_kernel(
    const ushort_t* __restrict__ A, const ushort_t* __restrict__ Bmat,
    const float* __restrict__ bias, float* __restrict__ fout,
    ushort_t* __restrict__ hout, ushort_t* __restrict__ ctxbf,
    const float* __restrict__ g_word, const float* __restrict__ svec) {
  __shared__ __align__(16) ushort_t lds[65536];  // 128 KB
  const int tid = threadIdx.x, lane = tid & 63, wave = tid >> 6;
  const int wr = wave >> 2, wc = wave & 3;  // 2 x 4
  const int nwg = 64 << NTSHIFT, cpx = nwg >> 3;
  int bid = blockIdx.x;
  int wg = (bid & 7) * cpx + (bid >> 3);
  const int bm = wg >> NTSHIFT, bn = wg & ((1 << NTSHIFT) - 1);
  const int NCOL = 256 << NTSHIFT;
  const int qsrc = (tid & 3) ^ ((tid >> 3) & 3);
  const ushort_t* sA0 = A + ((size_t)bm * 256 + (tid >> 2)) * 1024 + qsrc * 8;
  const ushort_t* sB0 = Bmat + ((size_t)bn * 256 + (tid >> 2)) * 1024 + qsrc * 8;
  const int qrd = (lane >> 4) ^ (((lane & 15) >> 1) & 3);
  const int aoff = (wr * 128 + (lane & 15)) * 32 + qrd * 8;
  const int boff = (wc * 64 + (lane & 15)) * 32 + qrd * 8;
  f32x4 acc[8][4] = {};
  stage2(sA0, lds, tid);
  stage2(sB0, lds + 32768, tid);
  stage2(sA0 + 32, lds + 8192, tid);
  stage2(sB0 + 32, lds + 32768 + 8192, tid);
  stage2(sA0 + 64, lds + 2 * 8192, tid);
  stage2(sB0 + 64, lds + 32768 + 2 * 8192, tid);
  wait_vm<8>();
  __builtin_amdgcn_s_barrier();
  for (int t = 0; t < 14; ++t)
    tile8<true, true, 8, 8>(t, sA0, sB0, lds, tid, aoff, boff, acc);
  tile8<true, false, 8, 4>(14, sA0, sB0, lds, tid, aoff, boff, acc);
  tile8<false, false, 0, -1>(15, sA0, sB0, lds, tid, aoff, boff, acc);
  // ---- epilogue ----
  #pragma unroll
  for (int m = 0; m < 8; m++) {
    #pragma unroll
    for (int i = 0; i < 4; i++) {
      int row = bm * 256 + wr * 128 + m * 16 + (lane >> 4) * 4 + i;
      float gw = 0.f;
      if constexpr (EPI == 3) gw = g_word[row];
      #pragma unroll
      for (int n = 0; n < 4; n++) {
        int col = bn * 256 + wc * 64 + n * 16 + (lane & 15);
        float v = acc[m][n][i];
        if constexpr (EPI == 0) {
          float z = v + bias[col];
          float gl = 0.5f * z * (1.f + erff(z * 0.70710678118f));
          hout[(size_t)row * 1024 + col] = f2bf1(gl);
        } else if constexpr (EPI == 1) {
          float z = v + bias[col];
          if constexpr (CTXB) ctxbf[(size_t)row * O_ + col] = f2bf1(z);
          else                fout[(size_t)row * NCOL + col] = z;
        } else {
          size_t off = (size_t)row * NCOL + col;
          float ctx = CTXB ? bf2f(ctxbf[(size_t)row * O_ + col]) : fout[off];
          float w = gw * sigmoidf(ctx);
          fout[off] = (1.f - w) * v + w * svec[col];
        }
      }
    }
  }
}

// ---------------- att: m97-style 128x128 simple 2-phase GEMM ----------------
template<bool CTXB>
__global__ __launch_bounds__(256, 3) void gemm128_att(
    const ushort_t* __restrict__ A, const ushort_t* __restrict__ Bmat,
    const float* __restrict__ bias, const float* __restrict__ fout,
    const ushort_t* __restrict__ ctxbf, float* __restrict__ mse_row) {
  __shared__ __align__(16) ushort_t As[128 * 32], Bs[128 * 32];
  const int tid = threadIdx.x, lane = tid & 63, wave = tid >> 6;
  const int wr = wave >> 1, wc = wave & 1;  // 2x2, 64x64 per wave
  int bid = blockIdx.x;
  int group = bid >> 7, within = bid & 127;
  int bm = group * 8 + (within & 7);
  int bn = within >> 3;  // 0..15
  f32x4 acc[4][4] = {};
  const ushort_t* Ap = A + (size_t)bm * 128 * 1024;
  const ushort_t* Bp = Bmat + (size_t)bn * 128 * 1024;
  const int r = lane & 15;
  const int qrd8 = ((lane >> 4) ^ ((r >> 1) & 3)) * 8;
  for (int k0 = 0; k0 < 1024; k0 += 32) {
    stage128s(Ap + k0, As, tid);
    stage128s(Bp + k0, Bs, tid);
    asm volatile("s_waitcnt vmcnt(0)" ::: "memory");
    __builtin_amdgcn_s_barrier();
    bf16x8 af[4], bf[4];
    #pragma unroll
    for (int m = 0; m < 4; m++) af[m] = *(const bf16x8*)&As[(wr * 64 + m * 16 + r) * 32 + qrd8];
    #pragma unroll
    for (int n = 0; n < 4; n++) bf[n] = *(const bf16x8*)&Bs[(wc * 64 + n * 16 + r) * 32 + qrd8];
    #pragma unroll
    for (int m = 0; m < 4; m++)
      #pragma unroll
      for (int n = 0; n < 4; n++) acc[m][n] = mfma16(af[m], bf[n], acc[m][n]);
    __builtin_amdgcn_s_barrier();
  }
  #pragma unroll
  for (int m = 0; m < 4; m++) {
    #pragma unroll
    for (int i = 0; i < 4; i++) {
      int row = bm * 128 + wr * 64 + m * 16 + (lane >> 4) * 4 + i;
      float msum = 0.f;
      #pragma unroll
      for (int n = 0; n < 4; n++) {
        int col = bn * 128 + wc * 64 + n * 16 + (lane & 15);
        float att = acc[m][n][i] + bias[col];
        float ctx = CTXB ? bf2f(ctxbf[(size_t)row * O_ + col])
                         : fout[(size_t)row * O_ + col];
        float d = ctx - att;
        msum += d * d;
      }
      #pragma unroll
      for (int o = 1; o < 16; o <<= 1) msum += __shfl_xor(msum, o, 64);
      if ((lane & 15) == 0) atomicAdd(&mse_row[row], msum);
    }
  }
}

// ---------------- K7: per-row log-softmax CE ----------------
__global__ __launch_bounds__(256) void ce_kernel(const float* __restrict__ logits,
    const int* __restrict__ labels, float* __restrict__ ce_row) {
  int row = blockIdx.x, t = threadIdx.x, lane = t & 63, wave = t >> 6;
  const float* lr = logits + (size_t)row * O_;
  float v[8];
  float m = -INFINITY;
  #pragma unroll
  for (int j = 0; j < 8; j++) { v[j] = lr[t + j * 256]; m = fmaxf(m, v[j]); }
  #pragma unroll
  for (int o = 32; o; o >>= 1) m = fmaxf(m, __shfl_xor(m, o, 64));
  __shared__ float red[8];
  if (lane == 0) red[wave] = m;
  __syncthreads();
  m = fmaxf(fmaxf(red[0], red[1]), fmaxf(red[2], red[3]));
  float se = 0.f;
  #pragma unroll
  for (int j = 0; j < 8; j++) se += expf(v[j] - m);
  se = wave_sum(se);
  if (lane == 0) red[4 + wave] = se;
  __syncthreads();
  if (t == 0) {
    float bs = red[4] + red[5] + red[6] + red[7];
    int lab = labels[row];
    float nll = 0.f;
    if (lab >= 0) nll = -(lr[lab] - m - logf(bs));
    ce_row[row] = nll;
  }
}

// ---------------- K8: final scalar ----------------
__global__ __launch_bounds__(256) void finalize_kernel(const float* __restrict__ ce_row,
    const float* __restrict__ mse_row, const int* __restrict__ labels,
    float* __restrict__ out0) {
  int t = threadIdx.x, lane = t & 63, wave = t >> 6;
  float sn = 0.f, sm = 0.f, sc = 0.f;
  for (int i = t; i < B_; i += 256) {
    if (labels[i] >= 0) { sn += ce_row[i]; sm += mse_row[i]; sc += 1.f; }
  }
  sn = wave_sum(sn); sm = wave_sum(sm); sc = wave_sum(sc);
  __shared__ float r0[4], r1[4], r2[4];
  if (lane == 0) { r0[wave] = sn; r1[wave] = sm; r2[wave] = sc; }
  __syncthreads();
  if (t == 0) {
    float a = r0[0] + r0[1] + r0[2] + r0[3];
    float b = r1[0] + r1[1] + r1[2] + r1[3];
    float c = r2[0] + r2[1] + r2[2] + r2[3];
    out0[0] = (a + LAM_ * (b / (float)O_)) / fmaxf(c, 1.f);
  }
}

// ---------------- launch ----------------
extern "C" void kernel_launch(void* const* d_in, const int* in_sizes, int n_in,
                              void* d_out, int out_size, void* d_ws, size_t ws_size,
                              hipStream_t stream) {
  const float* x        = (const float*)d_in[0];
  const float* x_ctx    = (const float*)d_in[1];
  const float* cls      = (const float*)d_in[2];
  const float* none_t   = (const float*)d_in[3];
  const float* ctx_q_w  = (const float*)d_in[4];
  const float* ctx_q_b  = (const float*)d_in[5];
  const float* word_g_w = (const float*)d_in[6];
  const float* word_g_b = (const float*)d_in[7];
  const float* w1       = (const float*)d_in[8];
  const float* b1       = (const float*)d_in[9];
  const float* w2       = (const float*)d_in[10];
  const float* b2       = (const float*)d_in[11];
  const float* hist     = (const float*)d_in[12];
  const int*   hcnt     = (const int*)d_in[13];
  const int*   labels   = (const int*)d_in[14];

  float* out  = (float*)d_out;
  float* out1 = out + 1;  // logits [B x O]
  char* ws = (char*)d_ws;

  ushort_t* xbf   = (ushort_t*)(ws + WS_XBF);
  ushort_t* xcbf  = (ushort_t*)(ws + WS_XCBF);
  ushort_t* hbf   = (ushort_t*)(ws + WS_HBF);
  ushort_t* clsbf = (ushort_t*)(ws + WS_CLSBF);
  ushort_t* ctwbf = (ushort_t*)(ws + WS_CTWBF);
  ushort_t* w2bf  = (ushort_t*)(ws + WS_W2BF);
  ushort_t* w1bf  = (ushort_t*)(ws + WS_W1BF);
  float* counts   = (float*)(ws + WS_SMALL + SM_COUNTS);
  float* tsum     = (float*)(ws + WS_SMALL + SM_TSUM);
  float* mse_row  = (float*)(ws + WS_SMALL + SM_MSE);
  float* s        = (float*)(ws + WS_SMALL + SM_S);
  float* g_word   = (float*)(ws + WS_SMALL + SM_GWORD);
  float* ce_row   = (float*)(ws + WS_SMALL + SM_CEROW);
  ushort_t* ctxbf = (ushort_t*)(ws + WS_CTXBF);
  const bool big  = ws_size >= WS_NEED_BIG;

  hipMemsetAsync(ws + WS_SMALL, 0, SM_ZERO_BYTES, stream);

  // fused: x -> bf16 + per-row dots
  rowdot_cvt_kernel<<<B_ / 4, 256, 0, stream>>>(x, cls, word_g_w, word_g_b, labels,
                                                xbf, tsum, counts, g_word);
  // one launch converts x_ctx, cls, ctx_q_w, w2, w1 to bf16
  {
    int n_xc  = B_ * D_ / 8;           // 2,097,152/8 = 262,144? (B*D=16.7M/8)
    int n_od  = O_ * D_ / 8;
    int n_dd  = D_ * D_ / 8;
    int c0 = n_xc, c1 = c0 + n_od, c2 = c1 + n_od, c3 = c2 + n_od, c4 = c3 + n_dd;
    f2bf_multi_kernel<<<(c4 + 255) / 256, 256, 0, stream>>>(
        x_ctx, xcbf, c0, cls, clsbf, c1, ctx_q_w, ctwbf, c2,
        w2, w2bf, c3, w1, w1bf, c4);
  }

  scls_kernel<<<O_ / 4, 256, 0, stream>>>(cls, none_t, hist, hcnt, counts, tsum, s);

  // h = gelu(x @ w1^T + b1)
  gemm8_kernel<0, 2, false><<<256, 512, 0, stream>>>(xbf, w1bf, b1, nullptr, hbf,
                                                     nullptr, nullptr, nullptr);
  // ctx = x_ctx @ ctx_q_w^T + ctx_b -> bf16 ctxbf (big) or f32 out1 (fallback)
  if (big)
    gemm8_kernel<1, 3, true><<<512, 512, 0, stream>>>(xcbf, ctwbf, ctx_q_b, out1,
                                                      nullptr, ctxbf, nullptr, nullptr);
  else
    gemm8_kernel<1, 3, false><<<512, 512, 0, stream>>>(xcbf, ctwbf, ctx_q_b, out1,
                                                       nullptr, nullptr, nullptr, nullptr);
  // att: 128^2 simple kernel; mse partials vs ctx
  if (big)
    gemm128_att<true><<<2048, 256, 0, stream>>>(hbf, w2bf, b2, out1, ctxbf, mse_row);
  else
    gemm128_att<false><<<2048, 256, 0, stream>>>(hbf, w2bf, b2, out1, nullptr, mse_row);
  // xc: plain gated-combine epilogue
  if (big)
    gemm8_kernel<3, 3, true><<<512, 512, 0, stream>>>(xbf, clsbf, nullptr, out1,
                                                      nullptr, ctxbf, g_word, s);
  else
    gemm8_kernel<3, 3, false><<<512, 512, 0, stream>>>(xbf, clsbf, nullptr, out1,
                                                       nullptr, nullptr, g_word, s);

  ce_kernel<<<B_, 256, 0, stream>>>(out1, labels, ce_row);
  finalize_kernel<<<1, 256, 0, stream>>>(ce_row, mse_row, labels, out);
}

// Round 15
// 428.254 us; speedup vs baseline: 8.3979x; 1.0014x over previous
//
#include <hip/hip_runtime.h>
#include <cstdint>
#include <cstddef>

#define DEV __device__ __forceinline__

typedef __attribute__((ext_vector_type(4))) float f32x4;
typedef __attribute__((ext_vector_type(8))) short bf16x8;
typedef unsigned short ushort_t;
typedef __attribute__((ext_vector_type(8))) unsigned short ushort8;

static constexpr int B_ = 16384, D_ = 1024, O_ = 2048;
static constexpr float LAM_ = 0.1f;

// ---------------- workspace layout (bytes) ----------------
static constexpr size_t WS_XBF   = 0;                               // B*D bf16
static constexpr size_t WS_XCBF  = WS_XBF   + (size_t)B_ * D_ * 2;  // B*D bf16
static constexpr size_t WS_HBF   = WS_XCBF  + (size_t)B_ * D_ * 2;  // B*D bf16
static constexpr size_t WS_CTWBF = WS_HBF   + (size_t)B_ * D_ * 2;  // O*D bf16
static constexpr size_t WS_W2BF  = WS_CTWBF + (size_t)O_ * D_ * 2;  // O*D bf16
static constexpr size_t WS_BCOMB = WS_W2BF  + (size_t)O_ * D_ * 2;  // (D+O)*D bf16: [w1; cls]
static constexpr size_t WS_SMALL = WS_BCOMB + (size_t)(D_ + O_) * D_ * 2;
// small block (byte offsets within WS_SMALL):
static constexpr size_t SM_COUNTS = 0;       // O f32   (zeroed)
static constexpr size_t SM_TSUM   = 8192;    // O f32   (zeroed)
static constexpr size_t SM_MSE    = 16384;   // B f32   (zeroed)
static constexpr size_t SM_ZERO_BYTES = 82176;
static constexpr size_t SM_S      = 82176;   // O f32   (fully overwritten)
static constexpr size_t SM_GWORD  = 90368;   // B f32   (fully overwritten)
static constexpr size_t SM_CEROW  = 155904;  // B f32   (fully overwritten)
// optional bf16 ctx buffer (used only if ws_size permits):
static constexpr size_t WS_CTXBF  = WS_SMALL + 2 * 1024 * 1024;
static constexpr size_t WS_NEED_BIG = WS_CTXBF + (size_t)B_ * O_ * 2;

// ---------------- helpers ----------------
DEV float wave_sum(float v) {
  #pragma unroll
  for (int o = 32; o; o >>= 1) v += __shfl_xor(v, o, 64);
  return v;
}

DEV ushort_t f2bf1(float f) {  // RNE float -> bf16 bits (finite inputs)
  union { float f; unsigned u; } c{f};
  unsigned r = c.u + 0x7fffu + ((c.u >> 16) & 1u);
  return (ushort_t)(r >> 16);
}

DEV float bf2f(ushort_t u) {
  union { unsigned u; float f; } c{(unsigned)u << 16};
  return c.f;
}

DEV float sigmoidf(float z) { return 1.0f / (1.0f + expf(-z)); }

DEV void gload_lds16(const ushort_t* g, ushort_t* l) {
  __builtin_amdgcn_global_load_lds((const __attribute__((address_space(1))) void*)g,
                                   (__attribute__((address_space(3))) void*)l, 16, 0, 0);
}

// stage one 256x32 bf16 K-half slot (16 KB) with 512 threads (2 x 16B chunks).
// T2: LDS dest linear, SOURCE quarter pre-swizzled; ds_read applies same involution.
DEV void stage2(const ushort_t* __restrict__ s0, ushort_t* slot, int tid) {
  gload_lds16(s0, slot + tid * 8);
  gload_lds16(s0 + 128 * 1024, slot + (tid + 512) * 8);
}

// stage a 128x32 tile with 256 threads (2 chunks each), T2-swizzled source quarter.
DEV void stage128s(const ushort_t* __restrict__ src, ushort_t* lds_, int tid) {
  int c0 = tid, c1 = tid + 256;
  int q0 = (c0 & 3) ^ ((c0 >> 3) & 3);
  int q1 = (c1 & 3) ^ ((c1 >> 3) & 3);
  gload_lds16(src + (size_t)(c0 >> 2) * 1024 + q0 * 8, lds_ + c0 * 8);
  gload_lds16(src + (size_t)(c1 >> 2) * 1024 + q1 * 8, lds_ + c1 * 8);
}

DEV f32x4 mfma16(bf16x8 a, bf16x8 b, f32x4 c) {
  return __builtin_amdgcn_mfma_f32_16x16x32_bf16(a, b, c, 0, 0, 0);
}

template<int N> DEV void wait_vm() {
  if constexpr (N == 8)      asm volatile("s_waitcnt vmcnt(8)" ::: "memory");
  else if constexpr (N == 4) asm volatile("s_waitcnt vmcnt(4)" ::: "memory");
  else if constexpr (N == 0) asm volatile("s_waitcnt vmcnt(0)" ::: "memory");
}

// ---------------- K1: multi-range f32 -> bf16 convert (1 launch for 5 arrays) ----------------
__global__ __launch_bounds__(256) void f2bf_multi_kernel(
    const float* __restrict__ s0, ushort_t* __restrict__ d0, int c0,
    const float* __restrict__ s1, ushort_t* __restrict__ d1, int c1,
    const float* __restrict__ s2, ushort_t* __restrict__ d2, int c2,
    const float* __restrict__ s3, ushort_t* __restrict__ d3, int c3,
    const float* __restrict__ s4, ushort_t* __restrict__ d4, int c4) {
  int i = blockIdx.x * 256 + threadIdx.x;
  const float* src; ushort_t* dst; int off;
  if (i < c0)      { src = s0; dst = d0; off = i; }
  else if (i < c1) { src = s1; dst = d1; off = i - c0; }
  else if (i < c2) { src = s2; dst = d2; off = i - c1; }
  else if (i < c3) { src = s3; dst = d3; off = i - c2; }
  else if (i < c4) { src = s4; dst = d4; off = i - c3; }
  else return;
  const float4* p = (const float4*)(src + (size_t)off * 8);
  float4 a = p[0], b = p[1];
  ushort8 o;
  o[0] = f2bf1(a.x); o[1] = f2bf1(a.y); o[2] = f2bf1(a.z); o[3] = f2bf1(a.w);
  o[4] = f2bf1(b.x); o[5] = f2bf1(b.y); o[6] = f2bf1(b.z); o[7] = f2bf1(b.w);
  *(ushort8*)(dst + (size_t)off * 8) = o;
}

// ---------------- K2: fused x->bf16 convert + per-row dots ----------------
__global__ __launch_bounds__(256) void rowdot_cvt_kernel(const float* __restrict__ x,
    const float* __restrict__ cls, const float* __restrict__ wg,
    const float* __restrict__ wgb, const int* __restrict__ labels,
    ushort_t* __restrict__ xbf,
    float* __restrict__ tsum, float* __restrict__ counts, float* __restrict__ g_word) {
  int wave = threadIdx.x >> 6, lane = threadIdx.x & 63;
  int row = blockIdx.x * 4 + wave;
  const float* xr = x + (size_t)row * D_;
  int lab = labels[row];
  const float* cr = cls + (size_t)max(lab, 0) * D_;
  float t = 0.f, g = 0.f;
  #pragma unroll
  for (int j = 0; j < 4; ++j) {
    int d = j * 256 + lane * 4;
    float4 xv = *(const float4*)(xr + d);
    float4 cv = *(const float4*)(cr + d);
    float4 wv = *(const float4*)(wg + d);
    t += xv.x * cv.x + xv.y * cv.y + xv.z * cv.z + xv.w * cv.w;
    g += xv.x * wv.x + xv.y * wv.y + xv.z * wv.z + xv.w * wv.w;
    uint2 pk;
    pk.x = (unsigned)f2bf1(xv.x) | ((unsigned)f2bf1(xv.y) << 16);
    pk.y = (unsigned)f2bf1(xv.z) | ((unsigned)f2bf1(xv.w) << 16);
    *(uint2*)(xbf + (size_t)row * D_ + d) = pk;
  }
  t = wave_sum(t); g = wave_sum(g);
  if (lane == 0) {
    if (lab >= 0) {
      atomicAdd(&tsum[lab], t);
      atomicAdd(&counts[lab], 1.0f);
    }
    g_word[row] = sigmoidf(g + wgb[0]);
  }
}

// ---------------- K3: s[o] = dot(r_sub[o], classifier[o]) ----------------
__global__ __launch_bounds__(256) void scls_kernel(const float* __restrict__ cls,
    const float* __restrict__ none_t, const float* __restrict__ hist,
    const int* __restrict__ hcnt, const float* __restrict__ counts,
    const float* __restrict__ tsum, float* __restrict__ s) {
  int wave = threadIdx.x >> 6, lane = threadIdx.x & 63;
  int o = blockIdx.x * 4 + wave;
  if (o >= O_) return;
  const float* cr = cls + (size_t)o * D_;
  const float* src = (o == 0) ? none_t : hist + (size_t)(o - 1) * D_;
  float dv = 0.f;
  #pragma unroll
  for (int j = 0; j < 4; ++j) {
    int d = j * 256 + lane * 4;
    float4 a = *(const float4*)(src + d);
    float4 c = *(const float4*)(cr + d);
    dv += a.x * c.x + a.y * c.y + a.z * c.z + a.w * c.w;
  }
  dv = wave_sum(dv);
  if (lane == 0) {
    if (o == 0) { s[0] = dv; }
    else {
      float co = counts[o];
      bool has = co > 0.f;
      int cnt = hcnt[o - 1] + (has ? 1 : 0);
      float denom = 1.f - powf(0.9f, (float)max(cnt, 1));
      float val = has ? (0.9f * dv + tsum[o] / fmaxf(co, 1.f)) : dv;
      s[o] = (0.1f / denom) * val;
    }
  }
}

// ---------------- r5 8-phase 256x256 GEMM K-loop (frozen schedule) ----------------
template<bool S01, bool S23, int W1, int W3>
DEV void tile8(int t, const ushort_t* __restrict__ sA0, const ushort_t* __restrict__ sB0,
               ushort_t* lds, int tid, int aoff, int boff, f32x4 (&acc)[8][4]) {
  const int k0 = 2 * t, k1 = 2 * t + 1;
  const ushort_t* As0 = lds + (k0 & 3) * 8192;
  const ushort_t* Bs0 = lds + 32768 + (k0 & 3) * 8192;
  const ushort_t* As1 = lds + (k1 & 3) * 8192;
  const ushort_t* Bs1 = lds + 32768 + (k1 & 3) * 8192;
  bf16x8 afr[4], bfr[4];
  #pragma unroll
  for (int n = 0; n < 4; n++) bfr[n] = *(const bf16x8*)&Bs0[boff + n * 512];
  #pragma unroll
  for (int m = 0; m < 4; m++) afr[m] = *(const bf16x8*)&As0[aoff + m * 512];
  if constexpr (S01) stage2(sA0 + (size_t)(2 * t + 3) * 32, lds + ((2 * t + 3) & 3) * 8192, tid);
  __builtin_amdgcn_s_barrier();
  __builtin_amdgcn_s_setprio(1);
  #pragma unroll
  for (int m = 0; m < 4; m++)
    #pragma unroll
    for (int n = 0; n < 4; n++) acc[m][n] = mfma16(afr[m], bfr[n], acc[m][n]);
  __builtin_amdgcn_s_setprio(0);
  __builtin_amdgcn_s_barrier();
  #pragma unroll
  for (int m = 0; m < 4; m++) afr[m] = *(const bf16x8*)&As0[aoff + (m + 4) * 512];
  if constexpr (S01) stage2(sB0 + (size_t)(2 * t + 3) * 32, lds + 32768 + ((2 * t + 3) & 3) * 8192, tid);
  __builtin_amdgcn_s_barrier();
  __builtin_amdgcn_s_setprio(1);
  #pragma unroll
  for (int m = 0; m < 4; m++)
    #pragma unroll
    for (int n = 0; n < 4; n++) acc[m + 4][n] = mfma16(afr[m], bfr[n], acc[m + 4][n]);
  __builtin_amdgcn_s_setprio(0);
  wait_vm<W1>();
  __builtin_amdgcn_s_barrier();
  #pragma unroll
  for (int n = 0; n < 4; n++) bfr[n] = *(const bf16x8*)&Bs1[boff + n * 512];
  #pragma unroll
  for (int m = 0; m < 4; m++) afr[m] = *(const bf16x8*)&As1[aoff + m * 512];
  if constexpr (S23) stage2(sA0 + (size_t)(2 * t + 4) * 32, lds + ((2 * t + 4) & 3) * 8192, tid);
  __builtin_amdgcn_s_barrier();
  __builtin_amdgcn_s_setprio(1);
  #pragma unroll
  for (int m = 0; m < 4; m++)
    #pragma unroll
    for (int n = 0; n < 4; n++) acc[m][n] = mfma16(afr[m], bfr[n], acc[m][n]);
  __builtin_amdgcn_s_setprio(0);
  __builtin_amdgcn_s_barrier();
  #pragma unroll
  for (int m = 0; m < 4; m++) afr[m] = *(const bf16x8*)&As1[aoff + (m + 4) * 512];
  if constexpr (S23) stage2(sB0 + (size_t)(2 * t + 4) * 32, lds + 32768 + ((2 * t + 4) & 3) * 8192, tid);
  __builtin_amdgcn_s_barrier();
  __builtin_amdgcn_s_setprio(1);
  #pragma unroll
  for (int m = 0; m < 4; m++)
    #pragma unroll
    for (int n = 0; n < 4; n++) acc[m + 4][n] = mfma16(afr[m], bfr[n], acc[m + 4][n]);
  __builtin_amdgcn_s_setprio(0);
  wait_vm<W3>();
  __builtin_amdgcn_s_barrier();
}

// EPI: 0 = h (bias+gelu -> bf16 hout); 1 = ctx (bias -> bf16 ctxbf or f32 fout)
//      3 = xc (read ctx; w = gw*sigmoid(ctx); fout = (1-w)*xc + w*s)
template<int EPI, int NTSHIFT, bool CTXB>
__global__ __launch_bounds__(512, 2) void gemm8_kernel(
    const ushort_t* __restrict__ A, const ushort_t* __restrict__ Bmat,
    const float* __restrict__ bias, float* __restrict__ fout,
    ushort_t* __restrict__ hout, ushort_t* __restrict__ ctxbf,
    const float* __restrict__ g_word, const float* __restrict__ svec) {
  __shared__ __align__(16) ushort_t lds[65536];  // 128 KB
  const int tid = threadIdx.x, lane = tid & 63, wave = tid >> 6;
  const int wr = wave >> 2, wc = wave & 3;  // 2 x 4
  const int nwg = 64 << NTSHIFT, cpx = nwg >> 3;
  int bid = blockIdx.x;
  int wg = (bid & 7) * cpx + (bid >> 3);
  const int bm = wg >> NTSHIFT, bn = wg & ((1 << NTSHIFT) - 1);
  const int NCOL = 256 << NTSHIFT;
  const int qsrc = (tid & 3) ^ ((tid >> 3) & 3);
  const ushort_t* sA0 = A + ((size_t)bm * 256 + (tid >> 2)) * 1024 + qsrc * 8;
  const ushort_t* sB0 = Bmat + ((size_t)bn * 256 + (tid >> 2)) * 1024 + qsrc * 8;
  const int qrd = (lane >> 4) ^ (((lane & 15) >> 1) & 3);
  const int aoff = (wr * 128 + (lane & 15)) * 32 + qrd * 8;
  const int boff = (wc * 64 + (lane & 15)) * 32 + qrd * 8;
  f32x4 acc[8][4] = {};
  stage2(sA0, lds, tid);
  stage2(sB0, lds + 32768, tid);
  stage2(sA0 + 32, lds + 8192, tid);
  stage2(sB0 + 32, lds + 32768 + 8192, tid);
  stage2(sA0 + 64, lds + 2 * 8192, tid);
  stage2(sB0 + 64, lds + 32768 + 2 * 8192, tid);
  wait_vm<8>();
  __builtin_amdgcn_s_barrier();
  for (int t = 0; t < 14; ++t)
    tile8<true, true, 8, 8>(t, sA0, sB0, lds, tid, aoff, boff, acc);
  tile8<true, false, 8, 4>(14, sA0, sB0, lds, tid, aoff, boff, acc);
  tile8<false, false, 0, -1>(15, sA0, sB0, lds, tid, aoff, boff, acc);
  // ---- epilogue ----
  #pragma unroll
  for (int m = 0; m < 8; m++) {
    #pragma unroll
    for (int i = 0; i < 4; i++) {
      int row = bm * 256 + wr * 128 + m * 16 + (lane >> 4) * 4 + i;
      float gw = 0.f;
      if constexpr (EPI == 3) gw = g_word[row];
      #pragma unroll
      for (int n = 0; n < 4; n++) {
        int col = bn * 256 + wc * 64 + n * 16 + (lane & 15);
        float v = acc[m][n][i];
        if constexpr (EPI == 0) {
          float z = v + bias[col];
          float gl = 0.5f * z * (1.f + erff(z * 0.70710678118f));
          hout[(size_t)row * 1024 + col] = f2bf1(gl);
        } else if constexpr (EPI == 1) {
          float z = v + bias[col];
          if constexpr (CTXB) ctxbf[(size_t)row * O_ + col] = f2bf1(z);
          else                fout[(size_t)row * NCOL + col] = z;
        } else {
          size_t off = (size_t)row * NCOL + col;
          float ctx = CTXB ? bf2f(ctxbf[(size_t)row * O_ + col]) : fout[off];
          float w = gw * sigmoidf(ctx);
          fout[off] = (1.f - w) * v + w * svec[col];
        }
      }
    }
  }
}

// ---------------- hxc: merged h + xc GEMM (A = xbf, B = [w1; cls], N = 3072) ----------------
// grid 64 m x 12 n = 768 blocks. bn 0..3 -> h region (gelu -> hbf);
// bn 4..11 -> xc region (gated combine with ctx -> out1 logits).
__global__ __launch_bounds__(512, 2) void hxc_kernel(
    const ushort_t* __restrict__ A, const ushort_t* __restrict__ Bmat,
    const float* __restrict__ b1, float* __restrict__ fout,
    ushort_t* __restrict__ hout, const ushort_t* __restrict__ ctxbf,
    const float* __restrict__ g_word, const float* __restrict__ svec) {
  __shared__ __align__(16) ushort_t lds[65536];
  const int tid = threadIdx.x, lane = tid & 63, wave = tid >> 6;
  const int wr = wave >> 2, wc = wave & 3;
  const int nwg = 768, cpx = nwg >> 3;  // 96; 768 % 8 == 0
  int bid = blockIdx.x;
  int wg = (bid & 7) * cpx + (bid >> 3);
  const int bm = wg / 12, bn = wg % 12;
  const int qsrc = (tid & 3) ^ ((tid >> 3) & 3);
  const ushort_t* sA0 = A + ((size_t)bm * 256 + (tid >> 2)) * 1024 + qsrc * 8;
  const ushort_t* sB0 = Bmat + ((size_t)bn * 256 + (tid >> 2)) * 1024 + qsrc * 8;
  const int qrd = (lane >> 4) ^ (((lane & 15) >> 1) & 3);
  const int aoff = (wr * 128 + (lane & 15)) * 32 + qrd * 8;
  const int boff = (wc * 64 + (lane & 15)) * 32 + qrd * 8;
  f32x4 acc[8][4] = {};
  stage2(sA0, lds, tid);
  stage2(sB0, lds + 32768, tid);
  stage2(sA0 + 32, lds + 8192, tid);
  stage2(sB0 + 32, lds + 32768 + 8192, tid);
  stage2(sA0 + 64, lds + 2 * 8192, tid);
  stage2(sB0 + 64, lds + 32768 + 2 * 8192, tid);
  wait_vm<8>();
  __builtin_amdgcn_s_barrier();
  for (int t = 0; t < 14; ++t)
    tile8<true, true, 8, 8>(t, sA0, sB0, lds, tid, aoff, boff, acc);
  tile8<true, false, 8, 4>(14, sA0, sB0, lds, tid, aoff, boff, acc);
  tile8<false, false, 0, -1>(15, sA0, sB0, lds, tid, aoff, boff, acc);
  // ---- epilogue: branch on region (wave-uniform: whole block is one region) ----
  if (bn < 4) {
    #pragma unroll
    for (int m = 0; m < 8; m++) {
      #pragma unroll
      for (int i = 0; i < 4; i++) {
        int row = bm * 256 + wr * 128 + m * 16 + (lane >> 4) * 4 + i;
        #pragma unroll
        for (int n = 0; n < 4; n++) {
          int col = bn * 256 + wc * 64 + n * 16 + (lane & 15);
          float z = acc[m][n][i] + b1[col];
          float gl = 0.5f * z * (1.f + erff(z * 0.70710678118f));
          hout[(size_t)row * 1024 + col] = f2bf1(gl);
        }
      }
    }
  } else {
    const int bnx = bn - 4;
    #pragma unroll
    for (int m = 0; m < 8; m++) {
      #pragma unroll
      for (int i = 0; i < 4; i++) {
        int row = bm * 256 + wr * 128 + m * 16 + (lane >> 4) * 4 + i;
        float gw = g_word[row];
        #pragma unroll
        for (int n = 0; n < 4; n++) {
          int col = bnx * 256 + wc * 64 + n * 16 + (lane & 15);
          size_t off = (size_t)row * O_ + col;
          float ctx = bf2f(ctxbf[off]);
          float w = gw * sigmoidf(ctx);
          fout[off] = (1.f - w) * acc[m][n][i] + w * svec[col];
        }
      }
    }
  }
}

// ---------------- att: m97-style 128x128 simple 2-phase GEMM ----------------
template<bool CTXB>
__global__ __launch_bounds__(256, 3) void gemm128_att(
    const ushort_t* __restrict__ A, const ushort_t* __restrict__ Bmat,
    const float* __restrict__ bias, const float* __restrict__ fout,
    const ushort_t* __restrict__ ctxbf, float* __restrict__ mse_row) {
  __shared__ __align__(16) ushort_t As[128 * 32], Bs[128 * 32];
  const int tid = threadIdx.x, lane = tid & 63, wave = tid >> 6;
  const int wr = wave >> 1, wc = wave & 1;
  int bid = blockIdx.x;
  int group = bid >> 7, within = bid & 127;
  int bm = group * 8 + (within & 7);
  int bn = within >> 3;
  f32x4 acc[4][4] = {};
  const ushort_t* Ap = A + (size_t)bm * 128 * 1024;
  const ushort_t* Bp = Bmat + (size_t)bn * 128 * 1024;
  const int r = lane & 15;
  const int qrd8 = ((lane >> 4) ^ ((r >> 1) & 3)) * 8;
  for (int k0 = 0; k0 < 1024; k0 += 32) {
    stage128s(Ap + k0, As, tid);
    stage128s(Bp + k0, Bs, tid);
    asm volatile("s_waitcnt vmcnt(0)" ::: "memory");
    __builtin_amdgcn_s_barrier();
    bf16x8 af[4], bf[4];
    #pragma unroll
    for (int m = 0; m < 4; m++) af[m] = *(const bf16x8*)&As[(wr * 64 + m * 16 + r) * 32 + qrd8];
    #pragma unroll
    for (int n = 0; n < 4; n++) bf[n] = *(const bf16x8*)&Bs[(wc * 64 + n * 16 + r) * 32 + qrd8];
    #pragma unroll
    for (int m = 0; m < 4; m++)
      #pragma unroll
      for (int n = 0; n < 4; n++) acc[m][n] = mfma16(af[m], bf[n], acc[m][n]);
    __builtin_amdgcn_s_barrier();
  }
  #pragma unroll
  for (int m = 0; m < 4; m++) {
    #pragma unroll
    for (int i = 0; i < 4; i++) {
      int row = bm * 128 + wr * 64 + m * 16 + (lane >> 4) * 4 + i;
      float msum = 0.f;
      #pragma unroll
      for (int n = 0; n < 4; n++) {
        int col = bn * 128 + wc * 64 + n * 16 + (lane & 15);
        float att = acc[m][n][i] + bias[col];
        float ctx = CTXB ? bf2f(ctxbf[(size_t)row * O_ + col])
                         : fout[(size_t)row * O_ + col];
        float d = ctx - att;
        msum += d * d;
      }
      #pragma unroll
      for (int o = 1; o < 16; o <<= 1) msum += __shfl_xor(msum, o, 64);
      if ((lane & 15) == 0) atomicAdd(&mse_row[row], msum);
    }
  }
}

// ---------------- K7: per-row log-softmax CE ----------------
__global__ __launch_bounds__(256) void ce_kernel(const float* __restrict__ logits,
    const int* __restrict__ labels, float* __restrict__ ce_row) {
  int row = blockIdx.x, t = threadIdx.x, lane = t & 63, wave = t >> 6;
  const float* lr = logits + (size_t)row * O_;
  float v[8];
  float m = -INFINITY;
  #pragma unroll
  for (int j = 0; j < 8; j++) { v[j] = lr[t + j * 256]; m = fmaxf(m, v[j]); }
  #pragma unroll
  for (int o = 32; o; o >>= 1) m = fmaxf(m, __shfl_xor(m, o, 64));
  __shared__ float red[8];
  if (lane == 0) red[wave] = m;
  __syncthreads();
  m = fmaxf(fmaxf(red[0], red[1]), fmaxf(red[2], red[3]));
  float se = 0.f;
  #pragma unroll
  for (int j = 0; j < 8; j++) se += expf(v[j] - m);
  se = wave_sum(se);
  if (lane == 0) red[4 + wave] = se;
  __syncthreads();
  if (t == 0) {
    float bs = red[4] + red[5] + red[6] + red[7];
    int lab = labels[row];
    float nll = 0.f;
    if (lab >= 0) nll = -(lr[lab] - m - logf(bs));
    ce_row[row] = nll;
  }
}

// ---------------- K8: final scalar ----------------
__global__ __launch_bounds__(256) void finalize_kernel(const float* __restrict__ ce_row,
    const float* __restrict__ mse_row, const int* __restrict__ labels,
    float* __restrict__ out0) {
  int t = threadIdx.x, lane = t & 63, wave = t >> 6;
  float sn = 0.f, sm = 0.f, sc = 0.f;
  for (int i = t; i < B_; i += 256) {
    if (labels[i] >= 0) { sn += ce_row[i]; sm += mse_row[i]; sc += 1.f; }
  }
  sn = wave_sum(sn); sm = wave_sum(sm); sc = wave_sum(sc);
  __shared__ float r0[4], r1[4], r2[4];
  if (lane == 0) { r0[wave] = sn; r1[wave] = sm; r2[wave] = sc; }
  __syncthreads();
  if (t == 0) {
    float a = r0[0] + r0[1] + r0[2] + r0[3];
    float b = r1[0] + r1[1] + r1[2] + r1[3];
    float c = r2[0] + r2[1] + r2[2] + r2[3];
    out0[0] = (a + LAM_ * (b / (float)O_)) / fmaxf(c, 1.f);
  }
}

// ---------------- launch ----------------
extern "C" void kernel_launch(void* const* d_in, const int* in_sizes, int n_in,
                              void* d_out, int out_size, void* d_ws, size_t ws_size,
                              hipStream_t stream) {
  const float* x        = (const float*)d_in[0];
  const float* x_ctx    = (const float*)d_in[1];
  const float* cls      = (const float*)d_in[2];
  const float* none_t   = (const float*)d_in[3];
  const float* ctx_q_w  = (const float*)d_in[4];
  const float* ctx_q_b  = (const float*)d_in[5];
  const float* word_g_w = (const float*)d_in[6];
  const float* word_g_b = (const float*)d_in[7];
  const float* w1       = (const float*)d_in[8];
  const float* b1       = (const float*)d_in[9];
  const float* w2       = (const float*)d_in[10];
  const float* b2       = (const float*)d_in[11];
  const float* hist     = (const float*)d_in[12];
  const int*   hcnt     = (const int*)d_in[13];
  const int*   labels   = (const int*)d_in[14];

  float* out  = (float*)d_out;
  float* out1 = out + 1;  // logits [B x O]
  char* ws = (char*)d_ws;

  ushort_t* xbf   = (ushort_t*)(ws + WS_XBF);
  ushort_t* xcbf  = (ushort_t*)(ws + WS_XCBF);
  ushort_t* hbf   = (ushort_t*)(ws + WS_HBF);
  ushort_t* ctwbf = (ushort_t*)(ws + WS_CTWBF);
  ushort_t* w2bf  = (ushort_t*)(ws + WS_W2BF);
  ushort_t* bcomb = (ushort_t*)(ws + WS_BCOMB);     // rows 0..1023 = w1, 1024..3071 = cls
  ushort_t* clspart = bcomb + (size_t)D_ * D_;      // cls rows within bcomb
  float* counts   = (float*)(ws + WS_SMALL + SM_COUNTS);
  float* tsum     = (float*)(ws + WS_SMALL + SM_TSUM);
  float* mse_row  = (float*)(ws + WS_SMALL + SM_MSE);
  float* s        = (float*)(ws + WS_SMALL + SM_S);
  float* g_word   = (float*)(ws + WS_SMALL + SM_GWORD);
  float* ce_row   = (float*)(ws + WS_SMALL + SM_CEROW);
  ushort_t* ctxbf = (ushort_t*)(ws + WS_CTXBF);
  const bool big  = ws_size >= WS_NEED_BIG;

  hipMemsetAsync(ws + WS_SMALL, 0, SM_ZERO_BYTES, stream);

  // fused: x -> bf16 + per-row dots
  rowdot_cvt_kernel<<<B_ / 4, 256, 0, stream>>>(x, cls, word_g_w, word_g_b, labels,
                                                xbf, tsum, counts, g_word);
  // one launch converts x_ctx, ctx_q_w, w2, w1->bcomb[0:1024), cls->bcomb[1024:3072)
  {
    int n_xc = B_ * D_ / 8, n_od = O_ * D_ / 8, n_dd = D_ * D_ / 8;
    int c0 = n_xc, c1 = c0 + n_od, c2 = c1 + n_od, c3 = c2 + n_dd, c4 = c3 + n_od;
    f2bf_multi_kernel<<<(c4 + 255) / 256, 256, 0, stream>>>(
        x_ctx, xcbf, c0, ctx_q_w, ctwbf, c1, w2, w2bf, c2,
        w1, bcomb, c3, cls, clspart, c4);
  }

  scls_kernel<<<O_ / 4, 256, 0, stream>>>(cls, none_t, hist, hcnt, counts, tsum, s);

  // ctx = x_ctx @ ctx_q_w^T + ctx_b -> bf16 ctxbf (big) or f32 out1 (fallback)
  if (big) {
    gemm8_kernel<1, 3, true><<<512, 512, 0, stream>>>(xcbf, ctwbf, ctx_q_b, out1,
                                                      nullptr, ctxbf, nullptr, nullptr);
    // merged h + xc (A = xbf, B = [w1; cls]); writes hbf and out1 logits
    hxc_kernel<<<768, 512, 0, stream>>>(xbf, bcomb, b1, out1, hbf, ctxbf, g_word, s);
    // att = h @ w2^T + b2 ; mse partials vs ctx (bf16)
    gemm128_att<true><<<2048, 256, 0, stream>>>(hbf, w2bf, b2, out1, ctxbf, mse_row);
  } else {
    gemm8_kernel<1, 3, false><<<512, 512, 0, stream>>>(xcbf, ctwbf, ctx_q_b, out1,
                                                       nullptr, nullptr, nullptr, nullptr);
    gemm8_kernel<0, 2, false><<<256, 512, 0, stream>>>(xbf, bcomb, b1, nullptr, hbf,
                                                       nullptr, nullptr, nullptr);
    gemm128_att<false><<<2048, 256, 0, stream>>>(hbf, w2bf, b2, out1, nullptr, mse_row);
    gemm8_kernel<3, 3, false><<<512, 512, 0, stream>>>(xbf, clspart, nullptr, out1,
                                                       nullptr, nullptr, g_word, s);
  }

  ce_kernel<<<B_, 256, 0, stream>>>(out1, labels, ce_row);
  finalize_kernel<<<1, 256, 0, stream>>>(ce_row, mse_row, labels, out);
}